// Round 8
// baseline (471.065 us; speedup 1.0000x reference)
//
#include <hip/hip_runtime.h>

#define SXD 256
#define SYD 256
#define SZD 32
#define NCOL (4 * SXD * SYD)              // 262144 z-columns
#define CIN 32
#define COUT 32
#define WT4_FLOATS (27 * 8 * 32 * 4)      // 27648 floats, 110 KB

// wt4[((k*8 + ci2)*32 + co)*4 + j] = w[co][ci2*4+j][k]   (w is (COUT,CIN,27) flat)
__global__ __launch_bounds__(256) void wt4_kernel(const float* __restrict__ w,
                                                  float* __restrict__ wt4) {
    int t = blockIdx.x * 256 + threadIdx.x;
    if (t >= WT4_FLOATS) return;
    int j   = t & 3;
    int co  = (t >> 2) & 31;
    int ci2 = (t >> 7) & 7;
    int k   = t >> 10;
    wt4[t] = w[(co * CIN + (ci2 * 4 + j)) * 27 + k];
}

// cols[c].x = z-occupancy bitmap of column c, cols[c].y = CSR base (filled by scan)
__global__ __launch_bounds__(256) void bitmap_kernel(const int* __restrict__ idx,
                                                     uint2* __restrict__ cols, int n) {
    int i = blockIdx.x * 256 + threadIdx.x;
    if (i >= n) return;
    int4 c = ((const int4*)idx)[i];                 // b,x,y,z
    int col = (c.x * SXD + c.y) * SYD + c.z;
    atomicOr(&cols[col].x, 1u << c.w);
}

// 3-kernel exclusive scan of popc over 262144 columns (256 blocks x 256 thr x 4 cols)
__global__ __launch_bounds__(256) void scan1_kernel(const uint2* __restrict__ cols,
                                                    unsigned* __restrict__ blocksum) {
    __shared__ unsigned s[256];
    int t = threadIdx.x;
    int c0 = (blockIdx.x * 256 + t) * 4;
    unsigned v = __popc(cols[c0].x) + __popc(cols[c0 + 1].x)
               + __popc(cols[c0 + 2].x) + __popc(cols[c0 + 3].x);
    s[t] = v; __syncthreads();
    for (int off = 128; off > 0; off >>= 1) {
        if (t < off) s[t] += s[t + off];
        __syncthreads();
    }
    if (t == 0) blocksum[blockIdx.x] = s[0];
}

__global__ __launch_bounds__(256) void scan2_kernel(const unsigned* __restrict__ blocksum,
                                                    unsigned* __restrict__ blockbase) {
    __shared__ unsigned s[256];
    int t = threadIdx.x;
    unsigned v = blocksum[t];
    s[t] = v; __syncthreads();
    for (int off = 1; off < 256; off <<= 1) {
        unsigned u = (t >= off) ? s[t - off] : 0u;
        __syncthreads();
        s[t] += u;
        __syncthreads();
    }
    blockbase[t] = s[t] - v;    // exclusive
}

__global__ __launch_bounds__(256) void scan3_kernel(uint2* __restrict__ cols,
                                                    const unsigned* __restrict__ blockbase) {
    __shared__ unsigned s[256];
    int t = threadIdx.x;
    int c0 = (blockIdx.x * 256 + t) * 4;
    unsigned p0 = __popc(cols[c0].x), p1 = __popc(cols[c0 + 1].x);
    unsigned p2 = __popc(cols[c0 + 2].x), p3 = __popc(cols[c0 + 3].x);
    unsigned sum = p0 + p1 + p2 + p3;
    s[t] = sum; __syncthreads();
    for (int off = 1; off < 256; off <<= 1) {
        unsigned u = (t >= off) ? s[t - off] : 0u;
        __syncthreads();
        s[t] += u;
        __syncthreads();
    }
    unsigned ex = s[t] - sum + blockbase[blockIdx.x];
    cols[c0].y     = ex;
    cols[c0 + 1].y = ex + p0;
    cols[c0 + 2].y = ex + p0 + p1;
    cols[c0 + 3].y = ex + p0 + p1 + p2;
}

// Scatter features into CSR (spatial) order; record packed coords + original id.
__global__ __launch_bounds__(256) void buildperm_kernel(
    const float* __restrict__ f, const int* __restrict__ idx,
    const uint2* __restrict__ cols, float* __restrict__ fsorted,
    unsigned* __restrict__ coordpk, int* __restrict__ orig, int n) {
    int wave = blockIdx.x * 4 + (threadIdx.x >> 6);
    int lane = threadIdx.x & 63;
    int half = lane >> 5;
    int ci   = lane & 31;
    int p    = wave * 2 + half;
    if (p >= n) return;
    int4 c = ((const int4*)idx)[p];
    int col = (c.x * SXD + c.y) * SYD + c.z;
    uint2 cb = cols[col];
    int pos = cb.y + __popc(cb.x & ((1u << c.w) - 1u));
    fsorted[(size_t)pos * CIN + ci] = f[(size_t)p * CIN + ci];
    if (ci == 0) {
        coordpk[pos] = ((((unsigned)c.x << 8 | (unsigned)c.y) << 8 | (unsigned)c.z) << 5) | (unsigned)c.w;
        orig[pos] = p;
    }
}

// Conv over CSR-sorted points. Wave = 2 points (half-wave each, lane = co).
// Probe: lane co (<27) tests bit in L2-resident uint2 CSR; rank via popc.
__global__ __launch_bounds__(256) void conv4_kernel(
    const float* __restrict__ fsorted, const unsigned* __restrict__ coordpk,
    const int* __restrict__ orig, const uint2* __restrict__ cols,
    const float* __restrict__ wt4, const float* __restrict__ bias,
    float* __restrict__ out, int n, int nwg) {
    // bijective XCD swizzle (m204): each XCD gets a contiguous chunk of sorted space
    int bid = blockIdx.x;
    int q = nwg >> 3, r = nwg & 7;
    int xcd = bid & 7, inner = bid >> 3;
    int wg = (xcd < r ? xcd * (q + 1) : r * (q + 1) + (xcd - r) * q) + inner;

    int wave = wg * 4 + (threadIdx.x >> 6);
    int lane = threadIdx.x & 63;
    int half = lane >> 5;
    int co   = lane & 31;
    int s    = wave * 2 + half;
    bool valid = s < n;

    int m = -1, op = 0;
    if (valid) {
        op = orig[s];
        unsigned pk = coordpk[s];
        if (co < 27) {
            int dx = co / 9 - 1;
            int dy = (co / 3) % 3 - 1;
            int dz = co % 3 - 1;
            int z = pk & 31, y = (pk >> 5) & 255, x = (pk >> 13) & 255, b = pk >> 21;
            int nx = x + dx, ny = y + dy, nz = z + dz;
            if ((unsigned)nx < SXD && (unsigned)ny < SYD && (unsigned)nz < SZD) {
                uint2 cb = cols[(b * SXD + nx) * SYD + ny];
                if ((cb.x >> nz) & 1u)
                    m = cb.y + __popc(cb.x & ((1u << nz) - 1u));
            }
        }
    }
    unsigned long long ball = __ballot(m >= 0);
    unsigned mymask = (unsigned)(ball >> (half * 32));

    float a0 = valid ? bias[co] : 0.0f;
    float a1 = 0.0f, a2 = 0.0f, a3 = 0.0f;

    while (mymask) {
        int k1 = __ffs(mymask) - 1; mymask &= mymask - 1;
        int k2 = -1;
        if (mymask) { k2 = __ffs(mymask) - 1; mymask &= mymask - 1; }

        int nbr1 = __shfl(m, (half << 5) + k1, 64);
        const float4* fr1 = (const float4*)(fsorted + (size_t)nbr1 * CIN);
        const float4* wr1 = (const float4*)wt4 + k1 * 256 + co;
        float4 F1[8], W1[8];
#pragma unroll
        for (int q2 = 0; q2 < 8; ++q2) { F1[q2] = fr1[q2]; W1[q2] = wr1[q2 * 32]; }

        if (k2 >= 0) {
            int nbr2 = __shfl(m, (half << 5) + k2, 64);
            const float4* fr2 = (const float4*)(fsorted + (size_t)nbr2 * CIN);
            const float4* wr2 = (const float4*)wt4 + k2 * 256 + co;
            float4 F2[8], W2[8];
#pragma unroll
            for (int q2 = 0; q2 < 8; ++q2) { F2[q2] = fr2[q2]; W2[q2] = wr2[q2 * 32]; }
#pragma unroll
            for (int q2 = 0; q2 < 4; ++q2) {
                a2 += F2[q2].x * W2[q2].x + F2[q2].y * W2[q2].y
                    + F2[q2].z * W2[q2].z + F2[q2].w * W2[q2].w;
                a3 += F2[q2 + 4].x * W2[q2 + 4].x + F2[q2 + 4].y * W2[q2 + 4].y
                    + F2[q2 + 4].z * W2[q2 + 4].z + F2[q2 + 4].w * W2[q2 + 4].w;
            }
        }
#pragma unroll
        for (int q2 = 0; q2 < 4; ++q2) {
            a0 += F1[q2].x * W1[q2].x + F1[q2].y * W1[q2].y
                + F1[q2].z * W1[q2].z + F1[q2].w * W1[q2].w;
            a1 += F1[q2 + 4].x * W1[q2 + 4].x + F1[q2 + 4].y * W1[q2 + 4].y
                + F1[q2 + 4].z * W1[q2 + 4].z + F1[q2 + 4].w * W1[q2 + 4].w;
        }
    }
    if (valid) out[(size_t)op * COUT + co] = (a0 + a1) + (a2 + a3);
}

extern "C" void kernel_launch(void* const* d_in, const int* in_sizes, int n_in,
                              void* d_out, int out_size, void* d_ws, size_t ws_size,
                              hipStream_t stream) {
    const float* f    = (const float*)d_in[0];
    const int* idx    = (const int*)d_in[1];
    const float* w    = (const float*)d_in[2];
    const float* bias = (const float*)d_in[3];
    float* out        = (float*)d_out;
    int n = in_sizes[0] / CIN;  // 400000

    auto align256 = [](size_t x) { return (x + 255) & ~(size_t)255; };
    char* base = (char*)d_ws;
    size_t off = 0;
    uint2*    cols      = (uint2*)(base + off);    off += align256((size_t)NCOL * 8);
    unsigned* blocksum  = (unsigned*)(base + off); off += align256(256 * 4);
    unsigned* blockbase = (unsigned*)(base + off); off += align256(256 * 4);
    float*    wt4       = (float*)(base + off);    off += align256((size_t)WT4_FLOATS * 4);
    unsigned* coordpk   = (unsigned*)(base + off); off += align256((size_t)n * 4);
    int*      orig      = (int*)(base + off);      off += align256((size_t)n * 4);
    float*    fsorted   = (float*)(base + off);    // n*CIN*4 = 51.2 MB

    // ws is re-poisoned before every launch: rebuild everything each call.
    hipMemsetAsync(cols, 0, (size_t)NCOL * 8, stream);
    wt4_kernel<<<(WT4_FLOATS + 255) / 256, 256, 0, stream>>>(w, wt4);
    bitmap_kernel<<<(n + 255) / 256, 256, 0, stream>>>(idx, cols, n);
    scan1_kernel<<<256, 256, 0, stream>>>(cols, blocksum);
    scan2_kernel<<<1, 256, 0, stream>>>(blocksum, blockbase);
    scan3_kernel<<<256, 256, 0, stream>>>(cols, blockbase);
    buildperm_kernel<<<(n + 7) / 8, 256, 0, stream>>>(f, idx, cols, fsorted, coordpk, orig, n);
    int nwg = (n + 7) / 8;
    conv4_kernel<<<nwg, 256, 0, stream>>>(fsorted, coordpk, orig, cols, wt4, bias, out, n, nwg);
}

// Round 9
// 278.571 us; speedup vs baseline: 1.6910x; 1.6910x over previous
//
#include <hip/hip_runtime.h>

#define SXD 256
#define SYD 256
#define SZD 32
#define NCOL (4 * SXD * SYD)              // 262144 z-columns
#define CIN 32
#define COUT 32
#define WB_ELEMS (27 * 32 * 32)           // bf16 weights [k][co][ci]

typedef __attribute__((ext_vector_type(8))) short short8v;
typedef __attribute__((ext_vector_type(4))) float float4v;

static __device__ __forceinline__ unsigned short f2bf(float v) {
    unsigned u = __float_as_uint(v);
    u += 0x7FFFu + ((u >> 16) & 1u);      // RNE
    return (unsigned short)(u >> 16);
}

// wb[(k*32 + co)*32 + ci] = bf16(w[co][ci][k])   (w is (COUT,CIN,27) flat)
__global__ __launch_bounds__(256) void wtb_kernel(const float* __restrict__ w,
                                                  unsigned short* __restrict__ wb) {
    int t = blockIdx.x * 256 + threadIdx.x;
    if (t >= WB_ELEMS) return;
    int ci = t & 31, co = (t >> 5) & 31, k = t >> 10;
    wb[(k * 32 + co) * 32 + ci] = f2bf(w[(co * CIN + ci) * 27 + k]);
}

// cols[c].x = z-occupancy bitmap, cols[c].y = CSR base (filled by scan)
__global__ __launch_bounds__(256) void bitmap_kernel(const int* __restrict__ idx,
                                                     uint2* __restrict__ cols, int n) {
    int i = blockIdx.x * 256 + threadIdx.x;
    if (i >= n) return;
    int4 c = ((const int4*)idx)[i];                 // b,x,y,z
    atomicOr(&cols[(c.x * SXD + c.y) * SYD + c.z].x, 1u << c.w);
}

__global__ __launch_bounds__(256) void scan1_kernel(const uint2* __restrict__ cols,
                                                    unsigned* __restrict__ blocksum) {
    __shared__ unsigned s[256];
    int t = threadIdx.x;
    int c0 = (blockIdx.x * 256 + t) * 4;
    unsigned v = __popc(cols[c0].x) + __popc(cols[c0 + 1].x)
               + __popc(cols[c0 + 2].x) + __popc(cols[c0 + 3].x);
    s[t] = v; __syncthreads();
    for (int off = 128; off > 0; off >>= 1) {
        if (t < off) s[t] += s[t + off];
        __syncthreads();
    }
    if (t == 0) blocksum[blockIdx.x] = s[0];
}

__global__ __launch_bounds__(256) void scan2_kernel(const unsigned* __restrict__ blocksum,
                                                    unsigned* __restrict__ blockbase) {
    __shared__ unsigned s[256];
    int t = threadIdx.x;
    unsigned v = blocksum[t];
    s[t] = v; __syncthreads();
    for (int off = 1; off < 256; off <<= 1) {
        unsigned u = (t >= off) ? s[t - off] : 0u;
        __syncthreads();
        s[t] += u;
        __syncthreads();
    }
    blockbase[t] = s[t] - v;    // exclusive
}

__global__ __launch_bounds__(256) void scan3_kernel(uint2* __restrict__ cols,
                                                    const unsigned* __restrict__ blockbase) {
    __shared__ unsigned s[256];
    int t = threadIdx.x;
    int c0 = (blockIdx.x * 256 + t) * 4;
    unsigned p0 = __popc(cols[c0].x), p1 = __popc(cols[c0 + 1].x);
    unsigned p2 = __popc(cols[c0 + 2].x), p3 = __popc(cols[c0 + 3].x);
    unsigned sum = p0 + p1 + p2 + p3;
    s[t] = sum; __syncthreads();
    for (int off = 1; off < 256; off <<= 1) {
        unsigned u = (t >= off) ? s[t - off] : 0u;
        __syncthreads();
        s[t] += u;
        __syncthreads();
    }
    unsigned ex = s[t] - sum + blockbase[blockIdx.x];
    cols[c0].y     = ex;
    cols[c0 + 1].y = ex + p0;
    cols[c0 + 2].y = ex + p0 + p1;
    cols[c0 + 3].y = ex + p0 + p1 + p2;
}

// Scatter features (as bf16) into CSR order; record packed coords + original id.
__global__ __launch_bounds__(256) void buildperm_kernel(
    const float* __restrict__ f, const int* __restrict__ idx,
    const uint2* __restrict__ cols, unsigned short* __restrict__ fb,
    unsigned* __restrict__ coordpk, int* __restrict__ orig, int n) {
    int wave = blockIdx.x * 4 + (threadIdx.x >> 6);
    int lane = threadIdx.x & 63;
    int half = lane >> 5;
    int ci   = lane & 31;
    int p    = wave * 2 + half;
    if (p >= n) return;
    int4 c = ((const int4*)idx)[p];
    uint2 cb = cols[(c.x * SXD + c.y) * SYD + c.z];
    int pos = cb.y + __popc(cb.x & ((1u << c.w) - 1u));
    fb[(size_t)pos * CIN + ci] = f2bf(f[(size_t)p * CIN + ci]);
    if (ci == 0) {
        coordpk[pos] = ((((unsigned)c.x << 8 | (unsigned)c.y) << 8 | (unsigned)c.z) << 5) | (unsigned)c.w;
        orig[pos] = p;
    }
}

// MFMA implicit-GEMM conv. Wave = 16-point output tile.
// Probe phase: 64 lanes cover 16pts x 27 offsets in 7 rounds -> LDS nbr table.
// GEMM phase: 27x { A[16x32]=gathered bf16 rows (1x16B load/lane, zero-row for
// misses); two mfma_f32_16x16x32_bf16 accumulate D[16pts][32co] }.
__global__ __launch_bounds__(256) void conv5_kernel(
    const unsigned short* __restrict__ fb, const unsigned* __restrict__ coordpk,
    const int* __restrict__ orig, const uint2* __restrict__ cols,
    const unsigned short* __restrict__ wb, const float* __restrict__ bias,
    float* __restrict__ out, int n, int nwg) {
    __shared__ int lnbr[4 * 448];           // [wave][k*16+pt], k<27

    // bijective XCD swizzle
    int bid = blockIdx.x;
    int q = nwg >> 3, r = nwg & 7;
    int xcd = bid & 7, inner = bid >> 3;
    int wg = (xcd < r ? xcd * (q + 1) : r * (q + 1) + (xcd - r) * q) + inner;

    int wv = threadIdx.x >> 6;
    int l  = threadIdx.x & 63;
    int pt = l & 15;                        // A-row / B-col / C-col lane role
    int qd = l >> 4;                        // quarter: k-slice for frags, row-group for C
    int base = (wg * 4 + wv) * 16;
    int s = base + pt;

    unsigned pk = (s < n) ? coordpk[s] : 0u;
    int z = pk & 31, y = (pk >> 5) & 255, x = (pk >> 13) & 255, b = pk >> 21;

#pragma unroll
    for (int rr = 0; rr < 7; ++rr) {
        int k = rr * 4 + qd;
        if (k < 27) {
            int nbr = n;                    // zero row
            int dx = k / 9 - 1, dy = (k / 3) % 3 - 1, dz = k % 3 - 1;
            int nx = x + dx, ny = y + dy, nz = z + dz;
            if ((unsigned)nx < SXD && (unsigned)ny < SYD && (unsigned)nz < SZD) {
                uint2 cb = cols[(b * SXD + nx) * SYD + ny];
                if ((cb.x >> nz) & 1u) nbr = cb.y + __popc(cb.x & ((1u << nz) - 1u));
            }
            lnbr[wv * 448 + k * 16 + pt] = nbr;
        }
    }
    __syncthreads();

    float4v c0 = {0.f, 0.f, 0.f, 0.f};
    float4v c1 = {0.f, 0.f, 0.f, 0.f};
#pragma unroll
    for (int k = 0; k < 27; ++k) {
        int nbr = lnbr[wv * 448 + k * 16 + pt];
        short8v a  = *(const short8v*)(fb + (size_t)nbr * CIN + qd * 8);
        short8v b0 = *(const short8v*)(wb + (k * 32 + pt) * 32 + qd * 8);
        short8v b1 = *(const short8v*)(wb + (k * 32 + pt + 16) * 32 + qd * 8);
        c0 = __builtin_amdgcn_mfma_f32_16x16x32_bf16(a, b0, c0, 0, 0, 0);
        c1 = __builtin_amdgcn_mfma_f32_16x16x32_bf16(a, b1, c1, 0, 0, 0);
    }

    float bv0 = bias[pt], bv1 = bias[pt + 16];
#pragma unroll
    for (int rr = 0; rr < 4; ++rr) {
        int srow = base + qd * 4 + rr;
        if (srow < n) {
            int o = orig[srow];
            out[(size_t)o * COUT + pt]      = c0[rr] + bv0;
            out[(size_t)o * COUT + 16 + pt] = c1[rr] + bv1;
        }
    }
}

extern "C" void kernel_launch(void* const* d_in, const int* in_sizes, int n_in,
                              void* d_out, int out_size, void* d_ws, size_t ws_size,
                              hipStream_t stream) {
    const float* f    = (const float*)d_in[0];
    const int* idx    = (const int*)d_in[1];
    const float* w    = (const float*)d_in[2];
    const float* bias = (const float*)d_in[3];
    float* out        = (float*)d_out;
    int n = in_sizes[0] / CIN;  // 400000

    auto align256 = [](size_t x) { return (x + 255) & ~(size_t)255; };
    char* basep = (char*)d_ws;
    size_t off = 0;
    uint2*          cols      = (uint2*)(basep + off);          off += align256((size_t)NCOL * 8);
    unsigned*       blocksum  = (unsigned*)(basep + off);       off += align256(256 * 4);
    unsigned*       blockbase = (unsigned*)(basep + off);       off += align256(256 * 4);
    unsigned short* wb        = (unsigned short*)(basep + off); off += align256((size_t)WB_ELEMS * 2);
    unsigned*       coordpk   = (unsigned*)(basep + off);       off += align256((size_t)n * 4);
    int*            orig      = (int*)(basep + off);            off += align256((size_t)n * 4);
    unsigned short* fb        = (unsigned short*)(basep + off); // (n+1)*32 bf16, ~25.6 MB

    // ws is re-poisoned before every launch: rebuild everything each call.
    hipMemsetAsync(cols, 0, (size_t)NCOL * 8, stream);
    hipMemsetAsync(fb + (size_t)n * CIN, 0, CIN * sizeof(unsigned short), stream); // zero row
    wtb_kernel<<<(WB_ELEMS + 255) / 256, 256, 0, stream>>>(w, wb);
    bitmap_kernel<<<(n + 255) / 256, 256, 0, stream>>>(idx, cols, n);
    scan1_kernel<<<256, 256, 0, stream>>>(cols, blocksum);
    scan2_kernel<<<1, 256, 0, stream>>>(blocksum, blockbase);
    scan3_kernel<<<256, 256, 0, stream>>>(cols, blockbase);
    buildperm_kernel<<<(n + 7) / 8, 256, 0, stream>>>(f, idx, cols, fb, coordpk, orig, n);
    int ntiles = (n + 15) / 16;
    int nwg = (ntiles + 3) / 4;
    conv5_kernel<<<nwg, 256, 0, stream>>>(fb, coordpk, orig, cols, wb, bias, out, n, nwg);
}